// Round 4
// baseline (683.120 us; speedup 1.0000x reference)
//
#include <hip/hip_runtime.h>
#include <hip/hip_cooperative_groups.h>
#include <math.h>

namespace cg = cooperative_groups;

#define NB 8
#define CIN 512
#define CM 32
#define HH 128
#define WW 128
#define HWSZ (HH*WW)
#define EPSF 1e-5f
#define COT_ITAU 1.25f   // 1/0.8
#define LAM 0.7f
#define GFLOOR 0.05f
#define TPB 512          // threads per block
#define NBLK 256         // one block per CU -> cooperative co-residency guaranteed
#define BPB 32           // blocks per batch image (16384/512)

__device__ __forceinline__ float wsum(float v){
#pragma unroll
  for (int o=32;o;o>>=1) v += __shfl_xor(v,o,64);
  return v;
}

// transpose compress weights [32][512] -> [512][32] for uniform scalar loads
__global__ void k_tw(const float* __restrict__ w, float* __restrict__ wT){
  int i = blockIdx.x*256 + threadIdx.x;
  if (i < CM*CIN){
    int c = i >> 9, k = i & (CIN-1);
    wT[k*CM + c] = w[i];
  }
}

struct MegaArgs {
  const float *x,*wT,*incg,*incb;
  const float *pjw,*pjg,*pjb,*chw,*chb,*cww,*cwb,*alpha,*beta;
  const float *kw,*vw,*a1w,*ag,*ab,*a2w,*fw,*fuw,*fg,*fb,*gw,*ew;
  float *out;
  float *statS,*statQ,*attS,*attQ,*esum,*fusS,*fusQ,*gsum;
  float *hpool,*wpart,*ah,*aw;
};

union ShU {
  float wp[CM][TPB];                                    // P2 pool staging (64 KB)
  struct {
    union { float pool[CM][WW]; float T[CM][HH+4]; } u; // P3 MLP (~17 KB)
    float sa[CM], sb[CM], smx[CM], ssc[CM];
  } mlp;
};

__global__ __launch_bounds__(TPB,2) void k_mega(MegaArgs A)
{
  cg::grid_group grid = cg::this_grid();
  __shared__ ShU sh;
  const int tid  = threadIdx.x;
  const int blk  = blockIdx.x;
  const int lane = tid & 63;
  const int p    = blk*TPB + tid;      // 0 .. 131071, one thread per position
  const int b    = p >> 14;
  const int pp   = p & (HWSZ-1);
  const int hrow = pp >> 7;
  const int wcol = pp & (WW-1);

  // ---------------- P1: compress (512->32) + instance-norm stats ----------------
  float xc[CM];
#pragma unroll
  for (int c=0;c<CM;c++) xc[c]=0.f;
  {
    const float* xb = A.x + ((size_t)b*CIN)*HWSZ + pp;
    float xv[8], xn[8];
#pragma unroll
    for (int u=0;u<8;u++) xv[u] = xb[(size_t)u*HWSZ];
    for (int i=0;i<CIN;i+=8){
      if (i+8<CIN){
#pragma unroll
        for (int u=0;u<8;u++) xn[u] = xb[(size_t)(i+8+u)*HWSZ];
      }
#pragma unroll
      for (int u=0;u<8;u++){
        const float* wr = A.wT + (i+u)*CM;   // uniform -> scalar loads
#pragma unroll
        for (int c=0;c<CM;c++) xc[c]=fmaf(wr[c],xv[u],xc[c]);
      }
#pragma unroll
      for (int u=0;u<8;u++) xv[u]=xn[u];
    }
  }
  {
    float ms=0.f,mq=0.f;
#pragma unroll
    for (int c=0;c<CM;c++){
      float s=wsum(xc[c]), q=wsum(xc[c]*xc[c]);
      if (lane==c){ms=s;mq=q;}
    }
    if (lane<CM){ atomicAdd(&A.statS[b*CM+lane],ms); atomicAdd(&A.statQ[b*CM+lane],mq); }
  }
  grid.sync();   // -------- sync 1 --------

  // ---------------- P2: norm, pools, k1 + att_pre + att stats ----------------
  float at[CM];
  {
    float nv[CM];
#pragma unroll
    for (int c=0;c<CM;c++){
      float mu  = A.statS[b*CM+c]*(1.f/HWSZ);
      float var = fmaf(-mu,mu, A.statQ[b*CM+c]*(1.f/HWSZ));
      float a   = rsqrtf(var+EPSF)*A.incg[c];
      nv[c] = fmaxf(0.f, fmaf(xc[c], a, A.incb[c]-mu*a));
    }
    // wpool block-partial via LDS (block = 4 rows of 128 cols)
#pragma unroll
    for (int c=0;c<CM;c++) sh.wp[c][tid]=nv[c];
    __syncthreads();
    if (tid<WW){
      float* wo = A.wpart + (size_t)blk*(CM*WW) + tid;
#pragma unroll
      for (int c=0;c<CM;c++)
        wo[c*WW] = sh.wp[c][tid]+sh.wp[c][tid+128]+sh.wp[c][tid+256]+sh.wp[c][tid+384];
    }
    // hpool via wave reduce + atomics (row uniform per wave)
    {
      float ms=0.f;
#pragma unroll
      for (int c=0;c<CM;c++){
        float s=wsum(nv[c]);
        if (lane==c) ms=s;
      }
      if (lane<CM) atomicAdd(&A.hpool[(b*CM+lane)*HH+hrow], ms*(1.f/WW));
    }
    // k1 then att_pre = att1(concat(k1, nv))
    float k1[CM];
#pragma unroll
    for (int g4=0;g4<4;g4++)
#pragma unroll
      for (int o=0;o<8;o++){
        float sk=0.f;
#pragma unroll
        for (int i=0;i<8;i++) sk=fmaf(A.kw[g4*64+o*8+i], nv[g4*8+i], sk);
        k1[g4*8+o]=sk;
      }
#pragma unroll
    for (int g4=0;g4<4;g4++)
#pragma unroll
      for (int o=0;o<8;o++){
        float s=0.f;
#pragma unroll
        for (int i=0;i<16;i++){
          float inp = (g4<2)? k1[g4*16+i] : nv[(g4-2)*16+i];
          s = fmaf(A.a1w[g4*128+o*16+i], inp, s);
        }
        at[g4*8+o]=s;
      }
    float ms=0.f,mq=0.f;
#pragma unroll
    for (int c=0;c<CM;c++){
      float s=wsum(at[c]), q=wsum(at[c]*at[c]);
      if (lane==c){ms=s;mq=q;}
    }
    if (lane<CM){ atomicAdd(&A.attS[b*CM+lane],ms); atomicAdd(&A.attQ[b*CM+lane],mq); }
  }
  grid.sync();   // -------- sync 2 --------

  // ---------------- P3: logits + esum; blocks<16: pool-reduce + coord MLP ----------------
  float l[CM];
  {
#pragma unroll
    for (int c=0;c<CM;c++){
      float mu  = A.attS[b*CM+c]*(1.f/HWSZ);
      float var = fmaf(-mu,mu, A.attQ[b*CM+c]*(1.f/HWSZ));
      float a   = rsqrtf(var+EPSF)*A.ag[c];
      at[c] = fmaxf(0.f, fmaf(at[c], a, A.ab[c]-mu*a));
    }
#pragma unroll
    for (int g4=0;g4<4;g4++)
#pragma unroll
      for (int o=0;o<8;o++){
        float s=0.f;
#pragma unroll
        for (int i=0;i<8;i++) s=fmaf(A.a2w[g4*64+o*8+i], at[g4*8+i], s);
        l[g4*8+o]=s;
      }
    float ms=0.f;
#pragma unroll
    for (int c=0;c<CM;c++){
      float s=wsum(__expf(l[c]*COT_ITAU));
      if (lane==c) ms=s;
    }
    if (lane<CM) atomicAdd(&A.esum[b*CM+lane], ms);
  }
  if (blk < 2*NB){
    const int bb = blk>>1, path = blk&1;
    float in[CM];
    if (path==1){
      // reduce wpart over this b's 32 blocks into LDS
      for (int t=tid; t<CM*WW; t+=TPB){
        const float* src = A.wpart + (size_t)(bb*BPB)*(CM*WW) + t;
        float s=0.f;
#pragma unroll 8
        for (int k=0;k<BPB;k++) s += src[(size_t)k*(CM*WW)];
        sh.mlp.u.pool[t>>7][t&127] = s*(1.f/HH);
      }
      __syncthreads();
      if (tid<HH){
#pragma unroll
        for (int c=0;c<CM;c++) in[c]=sh.mlp.u.pool[c][tid];
      }
      __syncthreads();   // before T overwrites pool
    } else {
      if (tid<HH){
#pragma unroll
        for (int c=0;c<CM;c++) in[c]=A.hpool[(bb*CM+c)*HH+tid];
      }
    }
    const float* w2 = (path==0)? A.chw : A.cww;
    const float* b2 = (path==0)? A.chb : A.cwb;
    float* outp     = (path==0)? A.ah  : A.aw;
    if (tid<HH){
#pragma unroll
      for (int g4=0;g4<4;g4++)
#pragma unroll
        for (int o=0;o<8;o++){
          float s=0.f;
#pragma unroll
          for (int i=0;i<8;i++) s=fmaf(A.pjw[g4*64+o*8+i], in[g4*8+i], s);
          sh.mlp.u.T[g4*8+o][tid]=s;
        }
    }
    __syncthreads();
    if (tid<CM){
      float s=0.f,q=0.f;
      for (int k=0;k<HH;k++){ float t=sh.mlp.u.T[tid][k]; s+=t; q+=t*t; }
      float mu=s*(1.f/HH);
      float var=q*(1.f/HH)-mu*mu;
      float a=rsqrtf(var+EPSF)*A.pjg[tid];
      sh.mlp.sa[tid]=a; sh.mlp.sb[tid]=A.pjb[tid]-mu*a;
    }
    __syncthreads();
    float z[CM];
    if (tid<HH){
      float sil[CM];
#pragma unroll
      for (int c=0;c<CM;c++){
        float val=fmaf(sh.mlp.u.T[c][tid], sh.mlp.sa[c], sh.mlp.sb[c]);
        sil[c]=val/(1.f+__expf(-val));
      }
#pragma unroll
      for (int g4=0;g4<4;g4++)
#pragma unroll
        for (int o=0;o<8;o++){
          float s=b2[g4*8+o];
#pragma unroll
          for (int i=0;i<8;i++) s=fmaf(w2[g4*64+o*8+i], sil[g4*8+i], s);
          z[g4*8+o]=s;
        }
    }
    __syncthreads();
    if (tid<HH){
#pragma unroll
      for (int c=0;c<CM;c++) sh.mlp.u.T[c][tid]=z[c];
    }
    __syncthreads();
    if (tid<CM){
      float mx=-1e30f;
      for (int k=0;k<HH;k++) mx=fmaxf(mx, sh.mlp.u.T[tid][k]);
      float s=0.f;
      for (int k=0;k<HH;k++) s+=__expf(sh.mlp.u.T[tid][k]-mx);
      sh.mlp.smx[tid]=mx; sh.mlp.ssc[tid]=(float)HH/s;
    }
    __syncthreads();
    if (tid<HH){
#pragma unroll
      for (int c=0;c<CM;c++)
        outp[(bb*CM+c)*HH+tid]=__expf(sh.mlp.u.T[c][tid]-sh.mlp.smx[c])*sh.mlp.ssc[c];
    }
  }
  grid.sync();   // -------- sync 3 --------

  // ---------------- P4: mix + cot_fuse + coord combine + fusion (+ fus stats) ----------------
  float fus[CM];
  {
    float nv[CM];
#pragma unroll
    for (int c=0;c<CM;c++){
      float mu  = A.statS[b*CM+c]*(1.f/HWSZ);
      float var = fmaf(-mu,mu, A.statQ[b*CM+c]*(1.f/HWSZ));
      float a   = rsqrtf(var+EPSF)*A.incg[c];
      nv[c] = fmaxf(0.f, fmaf(xc[c], a, A.incb[c]-mu*a));
    }
    float t[CM];
#pragma unroll
    for (int g4=0;g4<4;g4++)
#pragma unroll
      for (int o=0;o<8;o++){
        float sk=0.f,sv=0.f;
#pragma unroll
        for (int i=0;i<8;i++){
          float xv=nv[g4*8+i];
          sk=fmaf(A.kw[g4*64+o*8+i],xv,sk);
          sv=fmaf(A.vw[g4*64+o*8+i],xv,sv);
        }
        int c=g4*8+o;
        float lgv=l[c];
        float smv=__expf(lgv*COT_ITAU)*((float)HWSZ/A.esum[b*CM+c]);
        float sg=1.f/(1.f+__expf(-lgv));
        float mix=(1.f-LAM)*sg+LAM*smv;
        t[c]=fmaf(mix,sv,sk);
      }
    float co[CM];
    {
      float al=A.alpha[0], be=A.beta[0];
#pragma unroll
      for (int c=0;c<CM;c++){
        float wl = al*A.ah[(b*CM+c)*HH+hrow] + be*A.aw[(b*CM+c)*WW+wcol];
        co[c]=nv[c]*wl;   // kappa=1: xc*(1+(wl-1)) = xc*wl
      }
    }
    float cot[CM];
#pragma unroll
    for (int o=0;o<CM;o++){
      float s=0.f;
#pragma unroll
      for (int i=0;i<CM;i++) s=fmaf(A.fw[o*CM+i],t[i],s);
      cot[o]=s;
    }
#pragma unroll
    for (int o=0;o<CM;o++){
      float s=0.f;
#pragma unroll
      for (int i=0;i<CM;i++) s=fmaf(A.fuw[o*64+i],co[i],s);
#pragma unroll
      for (int i=0;i<CM;i++) s=fmaf(A.fuw[o*64+32+i],cot[i],s);
      fus[o]=s;
    }
    float ms=0.f,mq=0.f;
#pragma unroll
    for (int c=0;c<CM;c++){
      float s=wsum(fus[c]), q=wsum(fus[c]*fus[c]);
      if (lane==c){ms=s;mq=q;}
    }
    if (lane<CM){ atomicAdd(&A.fusS[b*CM+lane],ms); atomicAdd(&A.fusQ[b*CM+lane],mq); }
  }
  grid.sync();   // -------- sync 4 --------

  // ---------------- P5: gate statistic ----------------
  {
    float s=0.f;
#pragma unroll
    for (int c=0;c<CM;c++){
      float mu  = A.fusS[b*CM+c]*(1.f/HWSZ);
      float var = fmaf(-mu,mu, A.fusQ[b*CM+c]*(1.f/HWSZ));
      float a   = rsqrtf(var+EPSF)*A.fg[c];
      float g   = fmaxf(0.f, fmaf(fus[c], a, A.fb[c]-mu*a));
      s = fmaf(A.gw[c], g, s);
    }
    s = wsum(s);
    if (lane==0) atomicAdd(&A.gsum[b], s);
  }
  grid.sync();   // -------- sync 5 --------

  // ---------------- P6: gate + expand (32->512) ----------------
  {
    float gt = 1.f/(1.f+__expf(-A.gsum[b]*(1.f/HWSZ)));
    float sc = gt*(1.f-GFLOOR)+GFLOOR;
    float f[CM];
#pragma unroll
    for (int c=0;c<CM;c++){
      float mu  = A.fusS[b*CM+c]*(1.f/HWSZ);
      float var = fmaf(-mu,mu, A.fusQ[b*CM+c]*(1.f/HWSZ));
      float a   = rsqrtf(var+EPSF)*A.fg[c];
      f[c] = fmaxf(0.f, fmaf(fus[c], a, A.fb[c]-mu*a))*sc;
    }
    float* ob = A.out + ((size_t)b*CIN)*HWSZ + pp;
    for (int o=0;o<CIN;o+=2){
      const float* w0 = A.ew + (o+0)*CM;
      const float* w1 = A.ew + (o+1)*CM;
      float a0=0.f, a1=0.f;
#pragma unroll
      for (int c=0;c<CM;c++){
        a0=fmaf(w0[c],f[c],a0);
        a1=fmaf(w1[c],f[c],a1);
      }
      ob[(size_t)(o+0)*HWSZ]=a0;
      ob[(size_t)(o+1)*HWSZ]=a1;
    }
  }
}

extern "C" void kernel_launch(void* const* d_in, const int* in_sizes, int n_in,
                              void* d_out, int out_size, void* d_ws, size_t ws_size,
                              hipStream_t stream)
{
  const float* x    = (const float*)d_in[0];
  const float* cw   = (const float*)d_in[1];
  const float* incg = (const float*)d_in[2];
  const float* incb = (const float*)d_in[3];
  const float* pjw  = (const float*)d_in[4];
  const float* pjg  = (const float*)d_in[5];
  const float* pjb  = (const float*)d_in[6];
  const float* chw  = (const float*)d_in[7];
  const float* chb  = (const float*)d_in[8];
  const float* cww  = (const float*)d_in[9];
  const float* cwb  = (const float*)d_in[10];
  const float* alpha= (const float*)d_in[11];
  const float* beta = (const float*)d_in[12];
  const float* kw   = (const float*)d_in[13];
  const float* vw   = (const float*)d_in[14];
  const float* a1w  = (const float*)d_in[15];
  const float* ag   = (const float*)d_in[16];
  const float* ab   = (const float*)d_in[17];
  const float* a2w  = (const float*)d_in[18];
  const float* fw   = (const float*)d_in[19];
  const float* fuw  = (const float*)d_in[20];
  const float* fg   = (const float*)d_in[21];
  const float* fb   = (const float*)d_in[22];
  const float* gw   = (const float*)d_in[23];
  const float* ew   = (const float*)d_in[24];
  float* out = (float*)d_out;

  float* ws = (float*)d_ws;
  float* acc   = ws;                    // 2048 floats, zeroed
  float* statS = acc,       *statQ = acc+256;
  float* attS  = acc+512,   *attQ  = acc+768;
  float* esum  = acc+1024;
  float* fusS  = acc+1280,  *fusQ  = acc+1536;
  float* gsum  = acc+1792;
  float* hpool = ws + 2048;             // 32768 floats, zeroed (atomic-accumulated)
  float* wT    = hpool + (size_t)NB*CM*HH;
  float* wpart = wT + CM*CIN;           // NBLK*32*128 floats = 4 MB
  float* ah    = wpart + (size_t)NBLK*CM*WW;
  float* aw    = ah + (size_t)NB*CM*HH;

  hipMemsetAsync(acc, 0, (2048 + NB*CM*HH)*sizeof(float), stream);
  k_tw<<<64,256,0,stream>>>(cw, wT);

  MegaArgs margs;
  margs.x=x; margs.wT=wT; margs.incg=incg; margs.incb=incb;
  margs.pjw=pjw; margs.pjg=pjg; margs.pjb=pjb; margs.chw=chw; margs.chb=chb;
  margs.cww=cww; margs.cwb=cwb; margs.alpha=alpha; margs.beta=beta;
  margs.kw=kw; margs.vw=vw; margs.a1w=a1w; margs.ag=ag; margs.ab=ab; margs.a2w=a2w;
  margs.fw=fw; margs.fuw=fuw; margs.fg=fg; margs.fb=fb; margs.gw=gw; margs.ew=ew;
  margs.out=out;
  margs.statS=statS; margs.statQ=statQ; margs.attS=attS; margs.attQ=attQ;
  margs.esum=esum; margs.fusS=fusS; margs.fusQ=fusQ; margs.gsum=gsum;
  margs.hpool=hpool; margs.wpart=wpart; margs.ah=ah; margs.aw=aw;

  void* params[] = { (void*)&margs };
  hipLaunchCooperativeKernel((void*)k_mega, dim3(NBLK), dim3(TPB), params, 0, stream);
}

// Round 5
// 483.558 us; speedup vs baseline: 1.4127x; 1.4127x over previous
//
#include <hip/hip_runtime.h>
#include <math.h>

#define NB 8
#define CIN 512
#define CM 32
#define MG 8
#define HH 128
#define WW 128
#define HWSZ (HH*WW)
#define EPSF 1e-5f
#define COT_ITAU 1.25f   // 1/0.8
#define LAM 0.7f
#define GFLOOR 0.05f

__device__ __forceinline__ float wsum(float v){
#pragma unroll
  for (int o = 32; o; o >>= 1) v += __shfl_xor(v, o, 64);
  return v;
}

// transpose compress weights [32][512] -> [512][32]
__global__ void k_tw(const float* __restrict__ w, float* __restrict__ wT){
  int i = blockIdx.x*256 + threadIdx.x;
  if (i < CM*CIN){
    int c = i >> 9, k = i & (CIN-1);
    wT[k*CM + c] = w[i];
  }
}

// compress conv (512->32), K-split halves (blockIdx.y), 8-deep prefetch
__global__ __launch_bounds__(256) void k_compress(
    const float* __restrict__ x, const float* __restrict__ wT,
    float* __restrict__ part)
{
  int tid = threadIdx.x;
  int b = blockIdx.x >> 6;
  int p = ((blockIdx.x & 63) << 8) + tid;
  int half = blockIdx.y;
  const float* xb = x + ((size_t)b*CIN + half*256)*HWSZ + p;
  const float* wh = wT + half*256*CM;
  float acc[CM];
#pragma unroll
  for (int c=0;c<CM;c++) acc[c]=0.f;
  float xv[8], xn[8];
#pragma unroll
  for (int u=0;u<8;u++) xv[u] = xb[(size_t)u*HWSZ];
  for (int i=0;i<256;i+=8){
    if (i+8<256){
#pragma unroll
      for (int u=0;u<8;u++) xn[u] = xb[(size_t)(i+8+u)*HWSZ];
    }
#pragma unroll
    for (int u=0;u<8;u++){
      const float* wr = wh + (i+u)*CM;   // uniform -> scalar loads
#pragma unroll
      for (int c=0;c<CM;c++) acc[c]=fmaf(wr[c],xv[u],acc[c]);
    }
#pragma unroll
    for (int u=0;u<8;u++) xv[u]=xn[u];
  }
  float* yb = part + (size_t)half*NB*CM*HWSZ + ((size_t)b*CM)*HWSZ + p;
#pragma unroll
  for (int c=0;c<CM;c++) yb[(size_t)c*HWSZ] = acc[c];
}

// combine halves -> y, plus per-(b,c) sum/sumsq stats
__global__ __launch_bounds__(256) void k_comb(
    const float4* __restrict__ p0, const float4* __restrict__ p1,
    float4* __restrict__ y, float* __restrict__ s1, float* __restrict__ s2)
{
  int idx = blockIdx.x*256 + threadIdx.x;       // over NB*CM*HWSZ/4
  float4 a = p0[idx], bq = p1[idx];
  a.x+=bq.x; a.y+=bq.y; a.z+=bq.z; a.w+=bq.w;
  y[idx] = a;
  int bc = idx >> 12;                           // 4096 float4 per (b,c)
  float s = a.x+a.y+a.z+a.w;
  float q = a.x*a.x+a.y*a.y+a.z*a.z+a.w*a.w;
  s = wsum(s); q = wsum(q);
  if ((threadIdx.x&63)==0){ atomicAdd(&s1[bc],s); atomicAdd(&s2[bc],q); }
}

// sums -> premultiplied affine: xc = y*A + B
__global__ void k_finalize(const float* __restrict__ s1, const float* __restrict__ s2,
    const float* __restrict__ g, const float* __restrict__ bi,
    float* __restrict__ A, float* __restrict__ Bo, float cnt)
{
  int i = threadIdx.x;
  if (i < NB*CM){
    int c = i & (CM-1);
    float mu = s1[i]/cnt;
    float var = s2[i]/cnt - mu*mu;
    float a = rsqrtf(var+EPSF)*g[c];
    A[i]=a; Bo[i]=bi[c]-mu*a;
  }
}

// both pools in one pass: block per (b,c) plane
__global__ __launch_bounds__(256) void k_pools(const float* __restrict__ y,
    const float* __restrict__ A, const float* __restrict__ Bo,
    float* __restrict__ hpool, float* __restrict__ wpool)
{
  __shared__ float wsh[WW];
  int bc = blockIdx.x;
  int tid = threadIdx.x;
  float a=A[bc], bb=Bo[bc];
  if (tid<WW) wsh[tid]=0.f;
  __syncthreads();
  const float4* yp = (const float4*)(y + (size_t)bc*HWSZ);
  int cb = (4*tid) & 127;
  float w0=0.f,w1=0.f,w2=0.f,w3=0.f;
  for (int k=0;k<16;k++){
    int i = tid + 256*k;
    float4 t = yp[i];
    float v0=fmaxf(0.f,fmaf(t.x,a,bb)), v1=fmaxf(0.f,fmaf(t.y,a,bb));
    float v2=fmaxf(0.f,fmaf(t.z,a,bb)), v3=fmaxf(0.f,fmaf(t.w,a,bb));
    w0+=v0; w1+=v1; w2+=v2; w3+=v3;
    float rs = v0+v1+v2+v3;
    // reduce across the 32 lanes sharing this row (lanes same tid>>5 group)
#pragma unroll
    for (int o=16;o;o>>=1) rs += __shfl_xor(rs,o,64);
    if ((tid&31)==0){
      int row = i >> 5;
      hpool[bc*HH + row] = rs*(1.0f/WW);
    }
  }
  atomicAdd(&wsh[cb+0],w0); atomicAdd(&wsh[cb+1],w1);
  atomicAdd(&wsh[cb+2],w2); atomicAdd(&wsh[cb+3],w3);
  __syncthreads();
  if (tid<WW) wpool[bc*WW+tid] = wsh[tid]*(1.0f/HH);
}

// coord branch MLP: block per (b, path). 128 threads = positions.
__global__ __launch_bounds__(128) void k_coord(
    const float* __restrict__ hpool, const float* __restrict__ wpool,
    const float* __restrict__ w1, const float* __restrict__ g1, const float* __restrict__ b1,
    const float* __restrict__ hw_, const float* __restrict__ hb_,
    const float* __restrict__ ww_, const float* __restrict__ wb_,
    float* __restrict__ ah, float* __restrict__ aw)
{
  __shared__ float T[CM][HH+1];
  __shared__ float sa[CM], sb[CM], smx[CM], ssc[CM];
  int tid = threadIdx.x;
  int b = blockIdx.x >> 1;
  int path = blockIdx.x & 1;
  const float* pool = (path==0)? hpool : wpool;
  const float* w2   = (path==0)? hw_ : ww_;
  const float* b2   = (path==0)? hb_ : wb_;
  float* outp       = (path==0)? ah : aw;

  float in[CM];
#pragma unroll
  for (int c=0;c<CM;c++) in[c] = pool[(b*CM+c)*HH + tid];
#pragma unroll
  for (int gI=0;gI<4;gI++)
#pragma unroll
    for (int o=0;o<MG;o++){
      float s=0.f;
#pragma unroll
      for (int i=0;i<MG;i++) s = fmaf(w1[gI*64+o*8+i], in[gI*8+i], s);
      T[gI*8+o][tid] = s;
    }
  __syncthreads();
  if (tid < CM){
    float s=0.f, q=0.f;
    for (int k=0;k<HH;k++){ float t=T[tid][k]; s+=t; q+=t*t; }
    float mu = s*(1.0f/HH);
    float var = q*(1.0f/HH) - mu*mu;
    float a = rsqrtf(var+EPSF)*g1[tid];
    sa[tid]=a; sb[tid]=b1[tid]-mu*a;
  }
  __syncthreads();
  float z[CM];
  {
    float sil[CM];
#pragma unroll
    for (int c=0;c<CM;c++){
      float val = fmaf(T[c][tid], sa[c], sb[c]);
      sil[c] = val/(1.f+__expf(-val));
    }
#pragma unroll
    for (int gI=0;gI<4;gI++)
#pragma unroll
      for (int o=0;o<MG;o++){
        float s=b2[gI*8+o];
#pragma unroll
        for (int i=0;i<MG;i++) s = fmaf(w2[gI*64+o*8+i], sil[gI*8+i], s);
        z[gI*8+o]=s;
      }
  }
  __syncthreads();
#pragma unroll
  for (int c=0;c<CM;c++) T[c][tid]=z[c];
  __syncthreads();
  if (tid < CM){
    float mx=-1e30f;
    for (int k=0;k<HH;k++) mx = fmaxf(mx, T[tid][k]);
    float s=0.f;
    for (int k=0;k<HH;k++) s += __expf(T[tid][k]-mx);
    smx[tid]=mx; ssc[tid]=(float)HH/s;
  }
  __syncthreads();
#pragma unroll
  for (int c=0;c<CM;c++)
    outp[(b*CM+c)*HH + tid] = __expf(T[c][tid]-smx[c])*ssc[c];
}

// CoT part 1: att_pre only (+ att stats). k1/v recomputed later.
__global__ __launch_bounds__(256) void k_cot1(
  const float* __restrict__ y, const float* __restrict__ A, const float* __restrict__ Bo,
  const float* __restrict__ kw, const float* __restrict__ a1w,
  float* __restrict__ ao, float* __restrict__ s1, float* __restrict__ s2)
{
  int tid=threadIdx.x;
  int b = blockIdx.x >> 6;
  int p = ((blockIdx.x&63)<<8)+tid;
  size_t base = ((size_t)b*CM)*HWSZ + p;
  float xc[CM], k1[CM], at[CM];
#pragma unroll
  for (int c=0;c<CM;c++)
    xc[c] = fmaxf(0.f, fmaf(y[base+(size_t)c*HWSZ], A[b*CM+c], Bo[b*CM+c]));
#pragma unroll
  for (int gI=0;gI<4;gI++)
#pragma unroll
    for (int o=0;o<MG;o++){
      float sk=0.f;
#pragma unroll
      for (int i=0;i<MG;i++) sk = fmaf(kw[gI*64+o*8+i], xc[gI*MG+i], sk);
      k1[gI*MG+o]=sk;
    }
#pragma unroll
  for (int gI=0;gI<4;gI++)
#pragma unroll
    for (int o=0;o<MG;o++){
      float s=0.f;
#pragma unroll
      for (int i=0;i<16;i++){
        float inp = (gI<2) ? k1[gI*16+i] : xc[(gI-2)*16+i];
        s = fmaf(a1w[gI*128+o*16+i], inp, s);
      }
      at[gI*MG+o]=s;
    }
#pragma unroll
  for (int c=0;c<CM;c++) ao[base+(size_t)c*HWSZ]=at[c];
  float ms=0.f,mq=0.f;
#pragma unroll
  for (int c=0;c<CM;c++){
    float s=wsum(at[c]); float q=wsum(at[c]*at[c]);
    if ((tid&63)==c){ms=s;mq=q;}
  }
  int lane=tid&63;
  if (lane<CM){ atomicAdd(&s1[b*CM+lane],ms); atomicAdd(&s2[b*CM+lane],mq); }
}

// CoT part 2: softmax denominator only
__global__ __launch_bounds__(256) void k_cot2(
  const float* __restrict__ ao, const float* __restrict__ A, const float* __restrict__ Bo,
  const float* __restrict__ a2w, float* __restrict__ es)
{
  int tid=threadIdx.x;
  int b = blockIdx.x >> 6;
  int p = ((blockIdx.x&63)<<8)+tid;
  size_t base = ((size_t)b*CM)*HWSZ + p;
  float att[CM], l[CM];
#pragma unroll
  for (int c=0;c<CM;c++)
    att[c] = fmaxf(0.f, fmaf(ao[base+(size_t)c*HWSZ], A[b*CM+c], Bo[b*CM+c]));
#pragma unroll
  for (int gI=0;gI<4;gI++)
#pragma unroll
    for (int o=0;o<MG;o++){
      float s=0.f;
#pragma unroll
      for (int i=0;i<MG;i++) s = fmaf(a2w[gI*64+o*8+i], att[gI*8+i], s);
      l[gI*MG+o]=s;
    }
  float ms=0.f;
#pragma unroll
  for (int c=0;c<CM;c++){
    float s = wsum(__expf(l[c]*COT_ITAU));
    if ((tid&63)==c) ms=s;
  }
  int lane=tid&63;
  if (lane<CM) atomicAdd(&es[b*CM+lane], ms);
}

// recompute k1/v/logits, mix + cot_fuse + coord combine + fusion conv (+ fus stats)
__global__ __launch_bounds__(256) void k_mix_fuse(
  const float* __restrict__ y, const float* __restrict__ A, const float* __restrict__ Bo,
  const float* __restrict__ ao, const float* __restrict__ attA, const float* __restrict__ attB,
  const float* __restrict__ kw, const float* __restrict__ vw, const float* __restrict__ a2w,
  const float* __restrict__ ah, const float* __restrict__ awp, const float* __restrict__ es,
  const float* __restrict__ alpha, const float* __restrict__ beta,
  const float* __restrict__ fw, const float* __restrict__ fuw,
  float* __restrict__ fpo, float* __restrict__ s1, float* __restrict__ s2)
{
  int tid=threadIdx.x;
  int b = blockIdx.x>>6;
  int p = ((blockIdx.x&63)<<8)+tid;
  int h = p >> 7, w = p & (WW-1);
  size_t base = ((size_t)b*CM)*HWSZ + p;
  float al=alpha[0], be=beta[0];
  float xc[CM], att[CM], l[CM], t[CM];
#pragma unroll
  for (int c=0;c<CM;c++)
    xc[c] = fmaxf(0.f, fmaf(y[base+(size_t)c*HWSZ], A[b*CM+c], Bo[b*CM+c]));
#pragma unroll
  for (int c=0;c<CM;c++)
    att[c] = fmaxf(0.f, fmaf(ao[base+(size_t)c*HWSZ], attA[b*CM+c], attB[b*CM+c]));
#pragma unroll
  for (int gI=0;gI<4;gI++)
#pragma unroll
    for (int o=0;o<MG;o++){
      float s=0.f;
#pragma unroll
      for (int i=0;i<MG;i++) s = fmaf(a2w[gI*64+o*8+i], att[gI*8+i], s);
      l[gI*MG+o]=s;
    }
#pragma unroll
  for (int gI=0;gI<4;gI++)
#pragma unroll
    for (int o=0;o<MG;o++){
      float sk=0.f, sv=0.f;
#pragma unroll
      for (int i=0;i<MG;i++){
        float xv = xc[gI*MG+i];
        sk = fmaf(kw[gI*64+o*8+i], xv, sk);
        sv = fmaf(vw[gI*64+o*8+i], xv, sv);
      }
      int c = gI*MG+o;
      float lgv = l[c];
      float sm = __expf(lgv*COT_ITAU) * (16384.f/es[b*CM+c]);
      float sg = 1.f/(1.f+__expf(-lgv));
      float mix = (1.f-LAM)*sg + LAM*sm;
      t[c] = fmaf(mix, sv, sk);
    }
  float co[CM];
#pragma unroll
  for (int c=0;c<CM;c++){
    float wl = al*ah[(b*CM+c)*HH + h] + be*awp[(b*CM+c)*WW + w];
    co[c] = xc[c] * wl;   // kappa = 1
  }
  float cot[CM];
#pragma unroll
  for (int o=0;o<CM;o++){
    float s=0.f;
#pragma unroll
    for (int i=0;i<CM;i++) s = fmaf(fw[o*CM+i], t[i], s);
    cot[o]=s;
  }
  float ms=0.f, mq=0.f;
#pragma unroll
  for (int o=0;o<CM;o++){
    float s=0.f;
#pragma unroll
    for (int i=0;i<CM;i++) s = fmaf(fuw[o*64+i], co[i], s);
#pragma unroll
    for (int i=0;i<CM;i++) s = fmaf(fuw[o*64+32+i], cot[i], s);
    fpo[base+(size_t)o*HWSZ]=s;
    float ss = wsum(s); float qq = wsum(s*s);
    if ((tid&63)==o){ ms=ss; mq=qq; }
  }
  int lane=tid&63;
  if (lane<CM){ atomicAdd(&s1[b*CM+lane],ms); atomicAdd(&s2[b*CM+lane],mq); }
}

// gate statistics: sum of relu(norm(fused_pre)) per (b,c)
__global__ __launch_bounds__(256) void k_gstat(const float4* __restrict__ fp,
  const float* __restrict__ A, const float* __restrict__ Bo, float* __restrict__ gsum)
{
  int idx = blockIdx.x*256+threadIdx.x;  // NB*CM*HWSZ/4
  int bc = idx >> 12;
  float a=A[bc], bb=Bo[bc];
  float4 tv = fp[idx];
  float s = fmaxf(0.f,fmaf(tv.x,a,bb))+fmaxf(0.f,fmaf(tv.y,a,bb))
          + fmaxf(0.f,fmaf(tv.z,a,bb))+fmaxf(0.f,fmaf(tv.w,a,bb));
  s = wsum(s);
  if ((threadIdx.x&63)==0) atomicAdd(&gsum[bc], s);
}

__global__ void k_gate(const float* __restrict__ gsum, const float* __restrict__ gw,
                       float* __restrict__ scale){
  int b = threadIdx.x;
  if (b < NB){
    float s=0.f;
    for (int c=0;c<CM;c++) s += gw[c]*gsum[b*CM+c];
    s *= (1.0f/HWSZ);
    float gt = 1.f/(1.f+__expf(-s));
    scale[b] = gt*(1.f-GFLOOR)+GFLOOR;
  }
}

// expand conv 32->512: float2 positions, 128 output channels per block
__global__ __launch_bounds__(256) void k_expand(const float2* __restrict__ fp2,
  const float* __restrict__ A, const float* __restrict__ Bo,
  const float* __restrict__ ew, const float* __restrict__ scale, float2* __restrict__ out2)
{
  int tid = threadIdx.x;
  int b = blockIdx.x >> 5;
  int tile = blockIdx.x & 31;
  int f2 = tile*256 + tid;            // float2 idx within plane (0..8191)
  int og = blockIdx.y * 128;
  float sc = scale[b];
  float2 f[CM];
  const float2* fb = fp2 + ((size_t)b*CM)*(HWSZ/2) + f2;
#pragma unroll
  for (int c=0;c<CM;c++){
    float2 t = fb[(size_t)c*(HWSZ/2)];
    float a=A[b*CM+c], bb=Bo[b*CM+c];
    f[c].x = fmaxf(0.f, fmaf(t.x,a,bb))*sc;
    f[c].y = fmaxf(0.f, fmaf(t.y,a,bb))*sc;
  }
  float2* ob = out2 + ((size_t)b*CIN + og)*(HWSZ/2) + f2;
  for (int j=0;j<128;j++){
    const float* wr = ew + (og+j)*CM;   // uniform -> scalar loads
    float ax=0.f, ay=0.f;
#pragma unroll
    for (int c=0;c<CM;c++){
      float wv = wr[c];
      ax = fmaf(wv, f[c].x, ax);
      ay = fmaf(wv, f[c].y, ay);
    }
    float2 o2; o2.x=ax; o2.y=ay;
    ob[(size_t)j*(HWSZ/2)] = o2;
  }
}

extern "C" void kernel_launch(void* const* d_in, const int* in_sizes, int n_in,
                              void* d_out, int out_size, void* d_ws, size_t ws_size,
                              hipStream_t stream)
{
  const float* x    = (const float*)d_in[0];
  const float* cw   = (const float*)d_in[1];
  const float* incg = (const float*)d_in[2];
  const float* incb = (const float*)d_in[3];
  const float* pjw  = (const float*)d_in[4];
  const float* pjg  = (const float*)d_in[5];
  const float* pjb  = (const float*)d_in[6];
  const float* chw  = (const float*)d_in[7];
  const float* chb  = (const float*)d_in[8];
  const float* cww  = (const float*)d_in[9];
  const float* cwb  = (const float*)d_in[10];
  const float* alpha= (const float*)d_in[11];
  const float* beta = (const float*)d_in[12];
  const float* kw   = (const float*)d_in[13];
  const float* vw   = (const float*)d_in[14];
  const float* a1w  = (const float*)d_in[15];
  const float* ag   = (const float*)d_in[16];
  const float* ab   = (const float*)d_in[17];
  const float* a2w  = (const float*)d_in[18];
  const float* fw   = (const float*)d_in[19];
  const float* fuw  = (const float*)d_in[20];
  const float* fg   = (const float*)d_in[21];
  const float* fb   = (const float*)d_in[22];
  const float* gw   = (const float*)d_in[23];
  const float* ew   = (const float*)d_in[24];
  float* out = (float*)d_out;

  float* ws = (float*)d_ws;
  const size_t BIG = (size_t)NB*CM*HWSZ;  // 4,194,304 floats
  float* y    = ws;            // compressed pre-norm
  float* P    = ws +   BIG;    // att_pre
  float* F    = ws + 2*BIG;    // fused_pre; aliases part0 (dead before F written)
  float* part0= F;
  float* part1= ws + 3*BIG;
  float* sm   = ws + 4*BIG;
  float* wT    = sm;  sm += CM*CIN;
  float* hpool = sm;  sm += NB*CM*HH;
  float* wpool = sm;  sm += NB*CM*WW;
  float* ahB   = sm;  sm += NB*CM*HH;
  float* awB   = sm;  sm += NB*CM*WW;
  float* acc   = sm;  sm += 8*256;   // zeroed accumulators
  float* statS = acc,      *statQ = acc+256;
  float* attS  = acc+512,  *attQ  = acc+768;
  float* esum  = acc+1024;
  float* fusS  = acc+1280, *fusQ  = acc+1536;
  float* gsum  = acc+1792;
  float* normA = sm; sm+=256; float* normB = sm; sm+=256;
  float* attA  = sm; sm+=256; float* attB  = sm; sm+=256;
  float* fusA  = sm; sm+=256; float* fusB  = sm; sm+=256;
  float* scale = sm; sm+=64;

  hipMemsetAsync(acc, 0, 8*256*sizeof(float), stream);
  k_tw<<<64,256,0,stream>>>(cw, wT);
  k_compress<<<dim3(512,2),256,0,stream>>>(x, wT, part0);
  k_comb<<<4096,256,0,stream>>>((const float4*)part0,(const float4*)part1,(float4*)y,statS,statQ);
  k_finalize<<<1,256,0,stream>>>(statS,statQ,incg,incb,normA,normB,(float)HWSZ);
  k_pools<<<NB*CM,256,0,stream>>>(y,normA,normB,hpool,wpool);
  k_coord<<<16,128,0,stream>>>(hpool,wpool,pjw,pjg,pjb,chw,chb,cww,cwb,ahB,awB);
  k_cot1<<<512,256,0,stream>>>(y,normA,normB,kw,a1w,P,attS,attQ);
  k_finalize<<<1,256,0,stream>>>(attS,attQ,ag,ab,attA,attB,(float)HWSZ);
  k_cot2<<<512,256,0,stream>>>(P,attA,attB,a2w,esum);
  k_mix_fuse<<<512,256,0,stream>>>(y,normA,normB,P,attA,attB,kw,vw,a2w,ahB,awB,esum,alpha,beta,fw,fuw,F,fusS,fusQ);
  k_finalize<<<1,256,0,stream>>>(fusS,fusQ,fg,fb,fusA,fusB,(float)HWSZ);
  k_gstat<<<4096,256,0,stream>>>((const float4*)F, fusA,fusB,gsum);
  k_gate<<<1,64,0,stream>>>(gsum,gw,scale);
  k_expand<<<dim3(256,4),256,0,stream>>>((const float2*)F,fusA,fusB,ew,scale,(float2*)out);
}

// Round 7
// 355.957 us; speedup vs baseline: 1.9191x; 1.3585x over previous
//
#include <hip/hip_runtime.h>
#include <math.h>

#define NB 8
#define CIN 512
#define CM 32
#define MG 8
#define HH 128
#define WW 128
#define HWSZ (HH*WW)
#define EPSF 1e-5f
#define COT_ITAU 1.25f   // 1/0.8
#define LAM 0.7f
#define GFLOOR 0.05f

typedef float vf4 __attribute__((ext_vector_type(4)));

__device__ __forceinline__ float wsum(float v){
#pragma unroll
  for (int o = 32; o; o >>= 1) v += __shfl_xor(v, o, 64);
  return v;
}

// transpose compress weights [32][512] -> [512][32]
__global__ void k_tw(const float* __restrict__ w, float* __restrict__ wT){
  int i = blockIdx.x*256 + threadIdx.x;
  if (i < CM*CIN){
    int c = i >> 9, k = i & (CIN-1);
    wT[k*CM + c] = w[i];
  }
}

// compress conv (512->32), unsplit, 8-deep prefetch, nt loads; y + stats
__global__ __launch_bounds__(256) void k_compress(
    const float* __restrict__ x, const float* __restrict__ wT,
    float* __restrict__ y, float* __restrict__ s1, float* __restrict__ s2)
{
  int tid = threadIdx.x;
  int b = blockIdx.x >> 6;
  int p = ((blockIdx.x & 63) << 8) + tid;
  const float* xb = x + ((size_t)b*CIN)*HWSZ + p;
  float acc[CM];
#pragma unroll
  for (int c=0;c<CM;c++) acc[c]=0.f;
  float xv[8], xn[8];
#pragma unroll
  for (int u=0;u<8;u++) xv[u] = __builtin_nontemporal_load(&xb[(size_t)u*HWSZ]);
  for (int i=0;i<CIN;i+=8){
    if (i+8<CIN){
#pragma unroll
      for (int u=0;u<8;u++) xn[u] = __builtin_nontemporal_load(&xb[(size_t)(i+8+u)*HWSZ]);
    }
#pragma unroll
    for (int u=0;u<8;u++){
      const float* wr = wT + (i+u)*CM;   // uniform -> scalar loads
#pragma unroll
      for (int c=0;c<CM;c++) acc[c]=fmaf(wr[c],xv[u],acc[c]);
    }
#pragma unroll
    for (int u=0;u<8;u++) xv[u]=xn[u];
  }
  float* yb = y + ((size_t)b*CM)*HWSZ + p;
#pragma unroll
  for (int c=0;c<CM;c++) yb[(size_t)c*HWSZ] = acc[c];
  float ms=0.f, mq=0.f;
#pragma unroll
  for (int c=0;c<CM;c++){
    float s = wsum(acc[c]);
    float q = wsum(acc[c]*acc[c]);
    if ((tid&63)==c){ ms=s; mq=q; }
  }
  int lane = tid & 63;
  if (lane < CM){
    atomicAdd(&s1[b*CM+lane], ms);
    atomicAdd(&s2[b*CM+lane], mq);
  }
}

// sums -> premultiplied affine: xc = y*A + B
__global__ void k_finalize(const float* __restrict__ s1, const float* __restrict__ s2,
    const float* __restrict__ g, const float* __restrict__ bi,
    float* __restrict__ A, float* __restrict__ Bo, float cnt)
{
  int i = threadIdx.x;
  if (i < NB*CM){
    int c = i & (CM-1);
    float mu = s1[i]/cnt;
    float var = s2[i]/cnt - mu*mu;
    float a = rsqrtf(var+EPSF)*g[c];
    A[i]=a; Bo[i]=bi[c]-mu*a;
  }
}

// both pools, one pass: grid (bc=256, rowgroup=4); 32 rows/block, float4
__global__ __launch_bounds__(256) void k_pools(const float* __restrict__ y,
    const float* __restrict__ A, const float* __restrict__ Bo,
    float* __restrict__ hpool, float* __restrict__ wpool)
{
  __shared__ float colacc[WW];
  int bc = blockIdx.x;
  int rg = blockIdx.y;
  int tid = threadIdx.x;
  float a=A[bc], bb=Bo[bc];
  if (tid<WW) colacc[tid]=0.f;
  __syncthreads();
  const float4* yp = (const float4*)(y + (size_t)bc*HWSZ + (size_t)rg*32*WW);
  int col4 = tid & 31;
  float c0=0.f,c1=0.f,c2=0.f,c3=0.f;
#pragma unroll
  for (int it=0; it<4; ++it){
    int row = (tid>>5) + it*8;          // 0..31 within group
    float4 t = yp[row*32 + col4];
    float v0=fmaxf(0.f,fmaf(t.x,a,bb)), v1=fmaxf(0.f,fmaf(t.y,a,bb));
    float v2=fmaxf(0.f,fmaf(t.z,a,bb)), v3=fmaxf(0.f,fmaf(t.w,a,bb));
    c0+=v0; c1+=v1; c2+=v2; c3+=v3;
    float rs = v0+v1+v2+v3;
#pragma unroll
    for (int o=16;o;o>>=1) rs += __shfl_xor(rs,o,64);  // within 32-lane half (one row)
    if ((tid&31)==0) hpool[bc*HH + rg*32 + row] = rs*(1.0f/WW);
  }
  int cb = col4*4;
  atomicAdd(&colacc[cb+0],c0); atomicAdd(&colacc[cb+1],c1);
  atomicAdd(&colacc[cb+2],c2); atomicAdd(&colacc[cb+3],c3);
  __syncthreads();
  if (tid<WW) atomicAdd(&wpool[bc*WW+tid], colacc[tid]*(1.0f/HH));
}

// CoT part 1: att_pre only (+ att stats). k1/v recomputed later.
__global__ __launch_bounds__(256) void k_cot1(
  const float* __restrict__ y, const float* __restrict__ A, const float* __restrict__ Bo,
  const float* __restrict__ kw, const float* __restrict__ a1w,
  float* __restrict__ ao, float* __restrict__ s1, float* __restrict__ s2)
{
  int tid=threadIdx.x;
  int b = blockIdx.x >> 6;
  int p = ((blockIdx.x&63)<<8)+tid;
  size_t base = ((size_t)b*CM)*HWSZ + p;
  float xc[CM], k1[CM], at[CM];
#pragma unroll
  for (int c=0;c<CM;c++)
    xc[c] = fmaxf(0.f, fmaf(y[base+(size_t)c*HWSZ], A[b*CM+c], Bo[b*CM+c]));
#pragma unroll
  for (int gI=0;gI<4;gI++)
#pragma unroll
    for (int o=0;o<MG;o++){
      float sk=0.f;
#pragma unroll
      for (int i=0;i<MG;i++) sk = fmaf(kw[gI*64+o*8+i], xc[gI*MG+i], sk);
      k1[gI*MG+o]=sk;
    }
#pragma unroll
  for (int gI=0;gI<4;gI++)
#pragma unroll
    for (int o=0;o<MG;o++){
      float s=0.f;
#pragma unroll
      for (int i=0;i<16;i++){
        float inp = (gI<2) ? k1[gI*16+i] : xc[(gI-2)*16+i];
        s = fmaf(a1w[gI*128+o*16+i], inp, s);
      }
      at[gI*MG+o]=s;
    }
#pragma unroll
  for (int c=0;c<CM;c++) ao[base+(size_t)c*HWSZ]=at[c];
  float ms=0.f,mq=0.f;
#pragma unroll
  for (int c=0;c<CM;c++){
    float s=wsum(at[c]); float q=wsum(at[c]*at[c]);
    if ((tid&63)==c){ms=s;mq=q;}
  }
  int lane=tid&63;
  if (lane<CM){ atomicAdd(&s1[b*CM+lane],ms); atomicAdd(&s2[b*CM+lane],mq); }
}

// CoT part 2: softmax denominator; blocks 0..15 additionally run the coord MLP
__global__ __launch_bounds__(256) void k_cot2(
  const float* __restrict__ ao, const float* __restrict__ A, const float* __restrict__ Bo,
  const float* __restrict__ a2w,
  const float* __restrict__ hpool, const float* __restrict__ wpool,
  const float* __restrict__ pjw, const float* __restrict__ pjg, const float* __restrict__ pjb,
  const float* __restrict__ chw, const float* __restrict__ chb,
  const float* __restrict__ cww, const float* __restrict__ cwb,
  float* __restrict__ es, float* __restrict__ ah, float* __restrict__ aw)
{
  __shared__ float T[CM][HH+1];
  __shared__ float sa[CM], sb[CM], smx[CM], ssc[CM];
  int tid=threadIdx.x;
  int blk=blockIdx.x;
  int b = blk >> 6;
  int p = ((blk&63)<<8)+tid;
  size_t base = ((size_t)b*CM)*HWSZ + p;
  float att[CM], l[CM];
#pragma unroll
  for (int c=0;c<CM;c++)
    att[c] = fmaxf(0.f, fmaf(ao[base+(size_t)c*HWSZ], A[b*CM+c], Bo[b*CM+c]));
#pragma unroll
  for (int gI=0;gI<4;gI++)
#pragma unroll
    for (int o=0;o<MG;o++){
      float s=0.f;
#pragma unroll
      for (int i=0;i<MG;i++) s = fmaf(a2w[gI*64+o*8+i], att[gI*8+i], s);
      l[gI*MG+o]=s;
    }
  float ms=0.f;
#pragma unroll
  for (int c=0;c<CM;c++){
    float s = wsum(__expf(l[c]*COT_ITAU));
    if ((tid&63)==c) ms=s;
  }
  int lane=tid&63;
  if (lane<CM) atomicAdd(&es[b*CM+lane], ms);

  // ---- coord MLP (blocks 0..15): path 0 = H (hpool->ah), 1 = W (wpool->aw) ----
  if (blk < 2*NB){
    int bb = blk>>1, path = blk&1;
    const float* pool = path ? wpool : hpool;
    const float* w2   = path ? cww : chw;
    const float* b2   = path ? cwb : chb;
    float* outp       = path ? aw  : ah;
    float z[CM];
    if (tid<HH){
      float in[CM];
#pragma unroll
      for (int c=0;c<CM;c++) in[c] = pool[(bb*CM+c)*HH + tid];
#pragma unroll
      for (int gI=0;gI<4;gI++)
#pragma unroll
        for (int o=0;o<MG;o++){
          float s=0.f;
#pragma unroll
          for (int i=0;i<MG;i++) s = fmaf(pjw[gI*64+o*8+i], in[gI*8+i], s);
          T[gI*8+o][tid] = s;
        }
    }
    __syncthreads();
    if (tid < CM){
      float s=0.f, q=0.f;
      for (int k=0;k<HH;k++){ float t=T[tid][k]; s+=t; q+=t*t; }
      float mu = s*(1.0f/HH);
      float var = q*(1.0f/HH) - mu*mu;
      float a = rsqrtf(var+EPSF)*pjg[tid];
      sa[tid]=a; sb[tid]=pjb[tid]-mu*a;
    }
    __syncthreads();
    if (tid<HH){
      float sil[CM];
#pragma unroll
      for (int c=0;c<CM;c++){
        float val = fmaf(T[c][tid], sa[c], sb[c]);
        sil[c] = val/(1.f+__expf(-val));
      }
#pragma unroll
      for (int gI=0;gI<4;gI++)
#pragma unroll
        for (int o=0;o<MG;o++){
          float s=b2[gI*8+o];
#pragma unroll
          for (int i=0;i<MG;i++) s = fmaf(w2[gI*64+o*8+i], sil[gI*8+i], s);
          z[gI*8+o]=s;
        }
    }
    __syncthreads();
    if (tid<HH){
#pragma unroll
      for (int c=0;c<CM;c++) T[c][tid]=z[c];
    }
    __syncthreads();
    if (tid < CM){
      float mx=-1e30f;
      for (int k=0;k<HH;k++) mx = fmaxf(mx, T[tid][k]);
      float s=0.f;
      for (int k=0;k<HH;k++) s += __expf(T[tid][k]-mx);
      smx[tid]=mx; ssc[tid]=(float)HH/s;
    }
    __syncthreads();
    if (tid<HH){
#pragma unroll
      for (int c=0;c<CM;c++)
        outp[(bb*CM+c)*HH + tid] = __expf(T[c][tid]-smx[c])*ssc[c];
    }
  }
}

// recompute k1/v/logits, mix + cot_fuse + coord combine + fusion conv (+ fus stats)
__global__ __launch_bounds__(256) void k_mix_fuse(
  const float* __restrict__ y, const float* __restrict__ A, const float* __restrict__ Bo,
  const float* __restrict__ ao, const float* __restrict__ attA, const float* __restrict__ attB,
  const float* __restrict__ kw, const float* __restrict__ vw, const float* __restrict__ a2w,
  const float* __restrict__ ah, const float* __restrict__ awp, const float* __restrict__ es,
  const float* __restrict__ alpha, const float* __restrict__ beta,
  const float* __restrict__ fw, const float* __restrict__ fuw,
  float* __restrict__ fpo, float* __restrict__ s1, float* __restrict__ s2)
{
  int tid=threadIdx.x;
  int b = blockIdx.x>>6;
  int p = ((blockIdx.x&63)<<8)+tid;
  int h = p >> 7, w = p & (WW-1);
  size_t base = ((size_t)b*CM)*HWSZ + p;
  float al=alpha[0], be=beta[0];
  float xc[CM], att[CM], l[CM], t[CM];
#pragma unroll
  for (int c=0;c<CM;c++)
    xc[c] = fmaxf(0.f, fmaf(y[base+(size_t)c*HWSZ], A[b*CM+c], Bo[b*CM+c]));
#pragma unroll
  for (int c=0;c<CM;c++)
    att[c] = fmaxf(0.f, fmaf(ao[base+(size_t)c*HWSZ], attA[b*CM+c], attB[b*CM+c]));
#pragma unroll
  for (int gI=0;gI<4;gI++)
#pragma unroll
    for (int o=0;o<MG;o++){
      float s=0.f;
#pragma unroll
      for (int i=0;i<MG;i++) s = fmaf(a2w[gI*64+o*8+i], att[gI*8+i], s);
      l[gI*MG+o]=s;
    }
#pragma unroll
  for (int gI=0;gI<4;gI++)
#pragma unroll
    for (int o=0;o<MG;o++){
      float sk=0.f, sv=0.f;
#pragma unroll
      for (int i=0;i<MG;i++){
        float xv = xc[gI*MG+i];
        sk = fmaf(kw[gI*64+o*8+i], xv, sk);
        sv = fmaf(vw[gI*64+o*8+i], xv, sv);
      }
      int c = gI*MG+o;
      float lgv = l[c];
      float sm = __expf(lgv*COT_ITAU) * (16384.f/es[b*CM+c]);
      float sg = 1.f/(1.f+__expf(-lgv));
      float mix = (1.f-LAM)*sg + LAM*sm;
      t[c] = fmaf(mix, sv, sk);
    }
  float co[CM];
#pragma unroll
  for (int c=0;c<CM;c++){
    float wl = al*ah[(b*CM+c)*HH + h] + be*awp[(b*CM+c)*WW + w];
    co[c] = xc[c] * wl;   // kappa = 1
  }
  float cot[CM];
#pragma unroll
  for (int o=0;o<CM;o++){
    float s=0.f;
#pragma unroll
    for (int i=0;i<CM;i++) s = fmaf(fw[o*CM+i], t[i], s);
    cot[o]=s;
  }
  float ms=0.f, mq=0.f;
#pragma unroll
  for (int o=0;o<CM;o++){
    float s=0.f;
#pragma unroll
    for (int i=0;i<CM;i++) s = fmaf(fuw[o*64+i], co[i], s);
#pragma unroll
    for (int i=0;i<CM;i++) s = fmaf(fuw[o*64+32+i], cot[i], s);
    fpo[base+(size_t)o*HWSZ]=s;
    float ss = wsum(s); float qq = wsum(s*s);
    if ((tid&63)==o){ ms=ss; mq=qq; }
  }
  int lane=tid&63;
  if (lane<CM){ atomicAdd(&s1[b*CM+lane],ms); atomicAdd(&s2[b*CM+lane],mq); }
}

// gate statistics: sum of relu(norm(fused_pre)) per (b,c)
__global__ __launch_bounds__(256) void k_gstat(const float4* __restrict__ fp,
  const float* __restrict__ A, const float* __restrict__ Bo, float* __restrict__ gsum)
{
  int idx = blockIdx.x*256+threadIdx.x;  // NB*CM*HWSZ/4
  int bc = idx >> 12;
  float a=A[bc], bb=Bo[bc];
  float4 tv = fp[idx];
  float s = fmaxf(0.f,fmaf(tv.x,a,bb))+fmaxf(0.f,fmaf(tv.y,a,bb))
          + fmaxf(0.f,fmaf(tv.z,a,bb))+fmaxf(0.f,fmaf(tv.w,a,bb));
  s = wsum(s);
  if ((threadIdx.x&63)==0) atomicAdd(&gsum[bc], s);
}

__global__ void k_gate(const float* __restrict__ gsum, const float* __restrict__ gw,
                       float* __restrict__ scale){
  int b = threadIdx.x;
  if (b < NB){
    float s=0.f;
    for (int c=0;c<CM;c++) s += gw[c]*gsum[b*CM+c];
    s *= (1.0f/HWSZ);
    float gt = 1.f/(1.f+__expf(-s));
    scale[b] = gt*(1.f-GFLOOR)+GFLOOR;
  }
}

// expand conv 32->512: float4 positions, 64 output channels per block, nt stores
__global__ __launch_bounds__(256) void k_expand(const float4* __restrict__ fp4,
  const float* __restrict__ A, const float* __restrict__ Bo,
  const float* __restrict__ ew, const float* __restrict__ scale, vf4* __restrict__ out4)
{
  int tid = threadIdx.x;
  int b = blockIdx.x >> 4;
  int tile = blockIdx.x & 15;
  int p4 = tile*256 + tid;            // float4 idx within batch plane (0..4095)
  int og = blockIdx.y * 64;
  float sc = scale[b];
  float4 f[CM];
  const float4* fb = fp4 + ((size_t)b*CM)*(HWSZ/4) + p4;
#pragma unroll
  for (int c=0;c<CM;c++){
    float4 t = fb[(size_t)c*(HWSZ/4)];
    float a=A[b*CM+c], bb=Bo[b*CM+c];
    f[c].x = fmaxf(0.f, fmaf(t.x,a,bb))*sc;
    f[c].y = fmaxf(0.f, fmaf(t.y,a,bb))*sc;
    f[c].z = fmaxf(0.f, fmaf(t.z,a,bb))*sc;
    f[c].w = fmaxf(0.f, fmaf(t.w,a,bb))*sc;
  }
  vf4* ob = out4 + ((size_t)b*CIN + og)*(HWSZ/4) + p4;
  for (int j=0;j<64;j++){
    const float* wr = ew + (og+j)*CM;   // uniform -> scalar loads
    vf4 acc = (vf4)(0.f);
#pragma unroll
    for (int c=0;c<CM;c++){
      float wv = wr[c];
      acc.x = fmaf(wv, f[c].x, acc.x);
      acc.y = fmaf(wv, f[c].y, acc.y);
      acc.z = fmaf(wv, f[c].z, acc.z);
      acc.w = fmaf(wv, f[c].w, acc.w);
    }
    __builtin_nontemporal_store(acc, &ob[(size_t)j*(HWSZ/4)]);
  }
}

extern "C" void kernel_launch(void* const* d_in, const int* in_sizes, int n_in,
                              void* d_out, int out_size, void* d_ws, size_t ws_size,
                              hipStream_t stream)
{
  const float* x    = (const float*)d_in[0];
  const float* cw   = (const float*)d_in[1];
  const float* incg = (const float*)d_in[2];
  const float* incb = (const float*)d_in[3];
  const float* pjw  = (const float*)d_in[4];
  const float* pjg  = (const float*)d_in[5];
  const float* pjb  = (const float*)d_in[6];
  const float* chw  = (const float*)d_in[7];
  const float* chb  = (const float*)d_in[8];
  const float* cww  = (const float*)d_in[9];
  const float* cwb  = (const float*)d_in[10];
  const float* alpha= (const float*)d_in[11];
  const float* beta = (const float*)d_in[12];
  const float* kw   = (const float*)d_in[13];
  const float* vw   = (const float*)d_in[14];
  const float* a1w  = (const float*)d_in[15];
  const float* ag   = (const float*)d_in[16];
  const float* ab   = (const float*)d_in[17];
  const float* a2w  = (const float*)d_in[18];
  const float* fw   = (const float*)d_in[19];
  const float* fuw  = (const float*)d_in[20];
  const float* fg   = (const float*)d_in[21];
  const float* fb   = (const float*)d_in[22];
  const float* gw   = (const float*)d_in[23];
  const float* ew   = (const float*)d_in[24];
  float* out = (float*)d_out;

  float* ws = (float*)d_ws;
  const size_t BIG = (size_t)NB*CM*HWSZ;  // 4,194,304 floats (16 MiB)
  float* y    = ws;            // compressed pre-norm
  float* P    = ws +   BIG;    // att_pre
  float* F    = ws + 2*BIG;    // fused_pre
  float* sm   = ws + 3*BIG;
  float* acc   = sm;  sm += 2048;            // zeroed accumulators
  float* statS = acc,      *statQ = acc+256;
  float* attS  = acc+512,  *attQ  = acc+768;
  float* esum  = acc+1024;
  float* fusS  = acc+1280, *fusQ  = acc+1536;
  float* gsum  = acc+1792;
  float* wpool = sm;  sm += NB*CM*WW;        // zeroed (atomic-accumulated)
  float* wT    = sm;  sm += CM*CIN;
  float* hpool = sm;  sm += NB*CM*HH;        // direct-written
  float* ahB   = sm;  sm += NB*CM*HH;
  float* awB   = sm;  sm += NB*CM*WW;
  float* normA = sm; sm+=256; float* normB = sm; sm+=256;
  float* attA  = sm; sm+=256; float* attB  = sm; sm+=256;
  float* fusA  = sm; sm+=256; float* fusB  = sm; sm+=256;
  float* scale = sm; sm+=64;

  hipMemsetAsync(acc, 0, (2048 + NB*CM*WW)*sizeof(float), stream);
  k_tw<<<64,256,0,stream>>>(cw, wT);
  k_compress<<<512,256,0,stream>>>(x, wT, y, statS, statQ);
  k_finalize<<<1,256,0,stream>>>(statS,statQ,incg,incb,normA,normB,(float)HWSZ);
  k_pools<<<dim3(NB*CM,4),256,0,stream>>>(y,normA,normB,hpool,wpool);
  k_cot1<<<512,256,0,stream>>>(y,normA,normB,kw,a1w,P,attS,attQ);
  k_finalize<<<1,256,0,stream>>>(attS,attQ,ag,ab,attA,attB,(float)HWSZ);
  k_cot2<<<512,256,0,stream>>>(P,attA,attB,a2w,hpool,wpool,pjw,pjg,pjb,chw,chb,cww,cwb,esum,ahB,awB);
  k_mix_fuse<<<512,256,0,stream>>>(y,normA,normB,P,attA,attB,kw,vw,a2w,ahB,awB,esum,alpha,beta,fw,fuw,F,fusS,fusQ);
  k_finalize<<<1,256,0,stream>>>(fusS,fusQ,fg,fb,fusA,fusB,(float)HWSZ);
  k_gstat<<<4096,256,0,stream>>>((const float4*)F, fusA,fusB,gsum);
  k_gate<<<1,64,0,stream>>>(gsum,gw,scale);
  k_expand<<<dim3(128,8),256,0,stream>>>((const float4*)F,fusA,fusB,ew,scale,(vf4*)out);
}